// Round 12
// baseline (475.018 us; speedup 1.0000x reference)
//
#include <hip/hip_runtime.h>
#include <math.h>

#define S_LEN 2048
#define DMODEL 2560
#define NH 32
#define NKV 8
#define HD 128
#define QDIM (NH*HD)     // 4096
#define KVDIM (NKV*HD)   // 1024
#define NB (QDIM + 2*KVDIM)   // 6144 packed B rows
#define ROPE_THETA 5000000.0
#define QK_SCALE 0.08838834764831843f

typedef __attribute__((ext_vector_type(8))) short s16x8;
typedef __attribute__((ext_vector_type(4))) float f32x4;
typedef __attribute__((ext_vector_type(16))) float f32x16;
typedef unsigned short u16;

#define MFMA16(a,b,c) __builtin_amdgcn_mfma_f32_16x16x32_bf16((a),(b),(c),0,0,0)
#define MFMA32(a,b,c) __builtin_amdgcn_mfma_f32_32x32x16_bf16((a),(b),(c),0,0,0)

__device__ __forceinline__ u16 f2bf(float x) {
    union { float f; unsigned u; } v; v.f = x;
    unsigned r = v.u + 0x7FFFu + ((v.u >> 16) & 1u);
    return (u16)(r >> 16);
}
__device__ __forceinline__ float bf2f(u16 h) {
    union { unsigned u; float f; } v; v.u = ((unsigned)h) << 16;
    return v.f;
}
__device__ __forceinline__ unsigned pk2(float a, float b) {
    return (unsigned)f2bf(a) | ((unsigned)f2bf(b) << 16);
}

// K arrays: [rows][16 units of 8 bf16], XOR all 4 unit bits.
__device__ __forceinline__ int lswK(int row, int kb) {
    return ((row * 16 + (kb ^ (row & 15))) << 3);
}
// Packed [rows/2][8 units] tiles (qkv/o3): logical (row r, unit un 0..3)
// -> u16 index. Inverse of the stage mapping below.
__device__ __forceinline__ int lp8(int r, int un) {
    int rl = r >> 1, ulog = ((r & 1) << 2) | un;
    return (rl * 8 + (ulog ^ (rl & 7))) << 3;
}

// async global->LDS, 16B per lane; LDS dest = wave-uniform base + lane*16.
__device__ __forceinline__ void gload16(const void* g, void* l) {
    __builtin_amdgcn_global_load_lds(
        (const __attribute__((address_space(1))) void*)g,
        (__attribute__((address_space(3))) void*)l, 16, 0, 0);
}

// ---------------------------------------------------------------------------
// prep_all: all input-side elementwise work in ONE launch.
// ---------------------------------------------------------------------------
#define N4_X   (S_LEN*DMODEL/4)
#define N4_WQ  (QDIM*DMODEL/4)
#define N4_WKV (KVDIM*DMODEL/4)
#define N4_WO  (DMODEL*QDIM/4)
#define N_TAB  (S_LEN*64)
#define PREP_TOTAL (N4_X + N4_WQ + N4_WKV + N4_WKV + N4_WO + N_TAB)

__device__ __forceinline__ void split4(const float* in, long i,
                                       u16* hi, u16* lo) {
    float4 v = ((const float4*)in)[i];
    float a[4] = {v.x, v.y, v.z, v.w};
    u16 hh[4], ll[4];
    #pragma unroll
    for (int j = 0; j < 4; ++j) {
        hh[j] = f2bf(a[j]);
        ll[j] = f2bf(a[j] - bf2f(hh[j]));
    }
    ((uint2*)hi)[i] = make_uint2((unsigned)hh[0] | ((unsigned)hh[1] << 16),
                                 (unsigned)hh[2] | ((unsigned)hh[3] << 16));
    ((uint2*)lo)[i] = make_uint2((unsigned)ll[0] | ((unsigned)ll[1] << 16),
                                 (unsigned)ll[2] | ((unsigned)ll[3] << 16));
}
__device__ __forceinline__ void cvt4(const float* in, long i, u16* out) {
    float4 v = ((const float4*)in)[i];
    u16 h0 = f2bf(v.x), h1 = f2bf(v.y), h2 = f2bf(v.z), h3 = f2bf(v.w);
    ((uint2*)out)[i] = make_uint2((unsigned)h0 | ((unsigned)h1 << 16),
                                  (unsigned)h2 | ((unsigned)h3 << 16));
}

__global__ __launch_bounds__(256)
void prep_all(const float* __restrict__ x, const float* __restrict__ w_q,
              const float* __restrict__ w_k, const float* __restrict__ w_v,
              const float* __restrict__ w_o, const int* __restrict__ pos,
              u16* __restrict__ XH, u16* __restrict__ XL,
              u16* __restrict__ WBH, u16* __restrict__ WBL,
              u16* __restrict__ WOH,
              float* __restrict__ cost, float* __restrict__ sint) {
    long i = (long)blockIdx.x * 256 + threadIdx.x;
    if (i < N4_X) { split4(x, i, XH, XL); return; }
    i -= N4_X;
    if (i < N4_WQ) { split4(w_q, i, WBH, WBL); return; }
    i -= N4_WQ;
    if (i < N4_WKV) {
        split4(w_k, i, WBH + (size_t)QDIM * DMODEL, WBL + (size_t)QDIM * DMODEL);
        return;
    }
    i -= N4_WKV;
    if (i < N4_WKV) {
        split4(w_v, i, WBH + (size_t)(QDIM + KVDIM) * DMODEL,
                       WBL + (size_t)(QDIM + KVDIM) * DMODEL);
        return;
    }
    i -= N4_WKV;
    if (i < N4_WO) { cvt4(w_o, i, WOH); return; }
    i -= N4_WO;
    if (i < N_TAB) {
        int s = (int)(i >> 6), j = (int)(i & 63);
        double inv = pow((double)ROPE_THETA, -(double)j / 64.0);
        double ang = (double)pos[s] * inv;
        cost[i] = (float)cos(ang);
        sint[i] = (float)sin(ang);
    }
}

// ---------------------------------------------------------------------------
// merged rope: q (scaled, ws) + k (in-place fp32 cache) -> bf16 hi/lo splits
// ---------------------------------------------------------------------------
__global__ __launch_bounds__(256)
void rope_qk_split(float* __restrict__ q32, float* __restrict__ k,
                   const float* __restrict__ cost, const float* __restrict__ sint,
                   u16* __restrict__ qhh, u16* __restrict__ qll,
                   u16* __restrict__ khh, u16* __restrict__ kll) {
    int idx = blockIdx.x * 256 + threadIdx.x;
    if (idx < S_LEN * NH * 64) {
        int j = idx & 63;
        int h = (idx >> 6) & 31;
        int s = idx >> 11;
        float c = cost[(s << 6) + j], sn = sint[(s << 6) + j];
        size_t base = (size_t)s * QDIM + (size_t)h * HD;
        float x1 = q32[base + j], x2 = q32[base + 64 + j];
        float y1 = (x1 * c - x2 * sn) * QK_SCALE;
        float y2 = (x2 * c + x1 * sn) * QK_SCALE;
        u16 h1 = f2bf(y1), h2 = f2bf(y2);
        qhh[base + j] = h1;      qll[base + j] = f2bf(y1 - bf2f(h1));
        qhh[base + 64 + j] = h2; qll[base + 64 + j] = f2bf(y2 - bf2f(h2));
    } else {
        idx -= S_LEN * NH * 64;
        int j = idx & 63;
        int s = (idx >> 6) & 2047;
        int h = idx >> 17;
        float c = cost[(s << 6) + j], sn = sint[(s << 6) + j];
        size_t base = ((size_t)h * S_LEN + s) * HD;
        float x1 = k[base + j], x2 = k[base + 64 + j];
        float y1 = x1 * c - x2 * sn;
        float y2 = x2 * c + x1 * sn;
        k[base + j] = y1; k[base + 64 + j] = y2;
        u16 h1 = f2bf(y1), h2 = f2bf(y2);
        khh[base + j] = h1;      kll[base + j] = f2bf(y1 - bf2f(h1));
        khh[base + 64 + j] = h2; kll[base + 64 + j] = f2bf(y2 - bf2f(h2));
    }
}

// ---------------------------------------------------------------------------
// V^T builder: v [8][2048][128] fp32 -> vt [8][128][2048] bf16 (coalesced).
// ---------------------------------------------------------------------------
__global__ __launch_bounds__(256)
void vt_transpose(const float* __restrict__ v, u16* __restrict__ vt) {
    __shared__ u16 t[64][80];
    const int kvh = blockIdx.y;
    const int st = blockIdx.x >> 1, dt = blockIdx.x & 1;
    const int tid = threadIdx.x;
    const int r = tid & 15, c4 = (tid >> 4) * 4;
    const float* vb = v + ((size_t)kvh * S_LEN + st * 64) * HD + dt * 64;
    #pragma unroll
    for (int p = 0; p < 4; ++p) {
        int row = p * 16 + r;
        float4 x = *(const float4*)&vb[(size_t)row * HD + c4];
        t[c4 + 0][row] = f2bf(x.x);
        t[c4 + 1][row] = f2bf(x.y);
        t[c4 + 2][row] = f2bf(x.z);
        t[c4 + 3][row] = f2bf(x.w);
    }
    __syncthreads();
    #pragma unroll
    for (int p = 0; p < 2; ++p) {
        int idx = p * 256 + tid;
        int dr = idx >> 3, sc = idx & 7;
        size_t o = ((size_t)kvh * HD + dt * 64 + dr) * S_LEN + st * 64 + sc * 8;
        *(int4*)&vt[o] = *(const int4*)&t[dr][sc * 8];
    }
}

// ---------------------------------------------------------------------------
// gemm_qkv4: fused QKV projection, 32x32x16 MFMA + 2 blocks/CU.
// C[2048][6144] = sum over 3 segments (split-3: A=[XH,XH,XL], B=[WBH,WBL,WBH]).
// BM=128, BN=192, BK=32; 256 thr = 4 waves (2M x 2N), per-wave 64x96
// = 2x3 32-tiles. 2-slot ring (40KB LDS -> 2 blocks/CU); stage(j+1) issued
// a full window before its vmcnt(0) gate -> gate is normally free; the
// co-resident block hides residual stalls (m114 TLP).
// Grid 512 = 16m x 32n; bid&15 = m-tile -> A-panel XCD-pinned (m%8).
// ---------------------------------------------------------------------------
__global__ __launch_bounds__(256, 2)
void gemm_qkv4(const u16* __restrict__ XH, const u16* __restrict__ XL,
               const u16* __restrict__ WBH, const u16* __restrict__ WBL,
               float* __restrict__ Q32, float* __restrict__ out_k,
               float* __restrict__ out_v) {
    __shared__ u16 SM[20480];        // 2 slots x (A 4096 + B 6144) u16 = 40KB
    const int bid = blockIdx.x;
    const int m0 = (bid & 15) * 128;
    const int n0 = (bid >> 4) * 192;
    const int tid = threadIdx.x, lane = tid & 63, w = tid >> 6;
    const int r31 = lane & 31, hi = lane >> 5;
    const int wm = (w >> 1) * 64, wn = (w & 1) * 96;

    f32x16 acc[2][3];
    #pragma unroll
    for (int rt = 0; rt < 2; ++rt)
        #pragma unroll
        for (int ct = 0; ct < 3; ++ct) acc[rt][ct] = (f32x16)(0.0f);

    // stage k-window j (32 wide): A 8 chunks (2/wave), B 12 chunks (3/wave).
    auto stage = [&](int j) {
        const int s = j & 1;
        const int seg = j / 80;
        const int koff = (j - seg * 80) * 32;
        const u16* Ag = (seg == 2) ? XL : XH;
        const u16* Bg = (seg == 1) ? WBL : WBH;
        #pragma unroll
        for (int p = 0; p < 2; ++p) {
            int c = p * 4 + w;                    // 0..7
            int u = c * 64 + lane;
            int rl = u >> 3;
            int ulog = (u & 7) ^ (rl & 7);
            int grow = m0 + rl * 2 + (ulog >> 2);
            gload16(Ag + (size_t)grow * DMODEL + koff + (ulog & 3) * 8,
                    &SM[s * 10240 + c * 512]);
        }
        #pragma unroll
        for (int p = 0; p < 3; ++p) {
            int c = p * 4 + w;                    // 0..11
            int u = c * 64 + lane;
            int rl = u >> 3;
            int ulog = (u & 7) ^ (rl & 7);
            int grow = n0 + rl * 2 + (ulog >> 2);
            gload16(Bg + (size_t)grow * DMODEL + koff + (ulog & 3) * 8,
                    &SM[s * 10240 + 4096 + c * 512]);
        }
    };

    stage(0);

    const int NT = 3 * DMODEL / 32;   // 240
    for (int j = 0; j < NT; ++j) {
        const int s = j & 1;
        __builtin_amdgcn_sched_barrier(0);
        asm volatile("s_waitcnt vmcnt(0)" ::: "memory");   // stage(j) landed
        __builtin_amdgcn_s_barrier();                      // all waves past j-1
        __builtin_amdgcn_sched_barrier(0);
        if (j + 1 < NT) stage(j + 1);   // into slot (j+1)&1 (free since barrier)

        u16* As = SM + s * 10240;
        u16* Bs = As + 4096;
        #pragma unroll
        for (int kh = 0; kh < 2; ++kh) {
            int un = kh * 2 + hi;
            s16x8 af[2], bf[3];
            #pragma unroll
            for (int rt = 0; rt < 2; ++rt)
                af[rt] = *(const s16x8*)&As[lp8(wm + rt * 32 + r31, un)];
            #pragma unroll
            for (int ct = 0; ct < 3; ++ct)
                bf[ct] = *(const s16x8*)&Bs[lp8(wn + ct * 32 + r31, un)];
            __builtin_amdgcn_s_setprio(1);
            #pragma unroll
            for (int rt = 0; rt < 2; ++rt)
                #pragma unroll
                for (int ct = 0; ct < 3; ++ct)
                    acc[rt][ct] = MFMA32(af[rt], bf[ct], acc[rt][ct]);
            __builtin_amdgcn_s_setprio(0);
        }
    }

    // epilogue: 32x32 D layout: col = lane&31, row = (r&3)+8*(r>>2)+4*hi
    #pragma unroll
    for (int rt = 0; rt < 2; ++rt) {
        #pragma unroll
        for (int ct = 0; ct < 3; ++ct) {
            int col = n0 + wn + ct * 32 + r31;
            #pragma unroll
            for (int r = 0; r < 16; ++r) {
                int row = m0 + wm + rt * 32 + (r & 3) + 8 * (r >> 2) + 4 * hi;
                float v = acc[rt][ct][r];
                if (col < QDIM) {
                    Q32[(size_t)row * QDIM + col] = v;
                } else if (col < QDIM + KVDIM) {
                    int cc = col - QDIM;
                    out_k[((size_t)(cc >> 7) * S_LEN + row) * HD + (cc & 127)] = v;
                } else {
                    int cc = col - QDIM - KVDIM;
                    out_v[((size_t)(cc >> 7) * S_LEN + row) * HD + (cc & 127)] = v;
                }
            }
        }
    }
}

// ---------------------------------------------------------------------------
// gemm_o3: deep-pipelined O projection (plain bf16). (round-11, unchanged)
// ---------------------------------------------------------------------------
__global__ __launch_bounds__(256, 2)
void gemm_o3(const u16* __restrict__ AOH, const u16* __restrict__ WOH,
             float* __restrict__ out) {
    __shared__ u16 SM[36864];     // A: 4 x 4096 | B: 4 x 5120 (u16)
    const int bid = blockIdx.x;
    const int m0 = (bid & 15) * 128;
    const int n0 = (bid >> 4) * 160;
    const int tid = threadIdx.x, lane = tid & 63, w = tid >> 6;
    const int q4 = lane >> 4, r15 = lane & 15;
    const int wm = (w >> 1) * 64, wn = (w & 1) * 80;

    f32x4 acc[4][5];
    #pragma unroll
    for (int i = 0; i < 4; ++i)
        #pragma unroll
        for (int jj = 0; jj < 5; ++jj) acc[i][jj] = (f32x4)(0.0f);

    auto stageA = [&](int j) {
        const int s = j & 3;
        const int koff = j * 32;
        #pragma unroll
        for (int p = 0; p < 2; ++p) {
            int c = p * 4 + w;
            int u = c * 64 + lane;
            int rl = u >> 3;
            int ulog = (u & 7) ^ (rl & 7);
            int grow = m0 + rl * 2 + (ulog >> 2);
            gload16(AOH + (size_t)grow * QDIM + koff + (ulog & 3) * 8,
                    &SM[s * 4096 + c * 512]);
        }
    };
    auto stageB = [&](int j) {
        const int s = j & 3;
        const int koff = j * 32;
        #pragma unroll
        for (int p = 0; p < 3; ++p) {
            int c = p * 4 + w;
            if (c < 10) {
                int u = c * 64 + lane;
                int rl = u >> 3;
                int ulog = (u & 7) ^ (rl & 7);
                int grow = n0 + rl * 2 + (ulog >> 2);
                gload16(WOH + (size_t)grow * QDIM + koff + (ulog & 3) * 8,
                        &SM[16384 + s * 5120 + c * 512]);
            }
        }
    };

    stageA(0); stageB(0); stageA(1); stageB(1);

    const int NT = QDIM / 32;     // 128
    for (int j = 0; j < NT; ++j) {
        const int s = j & 3;
        __builtin_amdgcn_sched_barrier(0);
        if (j + 1 < NT) {
            if (w < 2) { asm volatile("s_waitcnt vmcnt(5)" ::: "memory"); }
            else       { asm volatile("s_waitcnt vmcnt(4)" ::: "memory"); }
        } else {
            asm volatile("s_waitcnt vmcnt(0)" ::: "memory");
        }
        __builtin_amdgcn_s_barrier();
        __builtin_amdgcn_sched_barrier(0);

        if (j + 2 < NT) stageA(j + 2);
        s16x8 bf[5];
        #pragma unroll
        for (int jj = 0; jj < 5; ++jj)
            bf[jj] = *(const s16x8*)&SM[16384 + s * 5120 + lp8(wn + jj * 16 + r15, q4)];
        s16x8 af01[2];
        #pragma unroll
        for (int i = 0; i < 2; ++i)
            af01[i] = *(const s16x8*)&SM[s * 4096 + lp8(wm + i * 16 + r15, q4)];
        __builtin_amdgcn_s_setprio(1);
        #pragma unroll
        for (int i = 0; i < 2; ++i)
            #pragma unroll
            for (int jj = 0; jj < 5; ++jj)
                acc[i][jj] = MFMA16(af01[i], bf[jj], acc[i][jj]);
        __builtin_amdgcn_s_setprio(0);

        if (j + 2 < NT) stageB(j + 2);
        s16x8 af23[2];
        #pragma unroll
        for (int i = 0; i < 2; ++i)
            af23[i] = *(const s16x8*)&SM[s * 4096 + lp8(wm + (i + 2) * 16 + r15, q4)];
        __builtin_amdgcn_s_setprio(1);
        #pragma unroll
        for (int i = 0; i < 2; ++i)
            #pragma unroll
            for (int jj = 0; jj < 5; ++jj)
                acc[i + 2][jj] = MFMA16(af23[i], bf[jj], acc[i + 2][jj]);
        __builtin_amdgcn_s_setprio(0);
    }

    #pragma unroll
    for (int i = 0; i < 4; ++i) {
        #pragma unroll
        for (int jj = 0; jj < 5; ++jj) {
            int col = n0 + wn + jj * 16 + r15;
            #pragma unroll
            for (int r = 0; r < 4; ++r) {
                int row = m0 + wm + i * 16 + q4 * 4 + r;
                out[(size_t)row * DMODEL + col] = acc[i][jj][r];
            }
        }
    }
}

// ---------------------------------------------------------------------------
// MFMA flash attention v9 (round-11, unchanged): swapped 32x32 QK^T,
// per-lane softmax, KVBLK=32, 3-slot ring, counted-vmcnt gates.
// ---------------------------------------------------------------------------
__global__ __launch_bounds__(256, 2)
void attn_mfma9(const u16* __restrict__ qh, const u16* __restrict__ ql,
                const u16* __restrict__ kh, const u16* __restrict__ kl,
                const u16* __restrict__ vt, u16* __restrict__ aoh) {
    const int bid = blockIdx.x;
    const int kvh = bid & 7;
    const int s6 = bid >> 3;
    const int qst = (s6 < 32) ? s6 : 95 - s6;
    const int KT = qst + 1;

    const int tid = threadIdx.x, lane = tid & 63, w = tid >> 6;
    const int head = kvh * 4 + w;
    const int col = lane & 31;
    const int hi = lane >> 5;

    __shared__ u16 SMEM[36864];

    s16x8 qfh[8], qfl[8];
    {
        size_t qrow = (size_t)qst * 32 + col;
        const u16* qb  = qh + qrow * QDIM + (size_t)head * HD + hi * 8;
        const u16* qb2 = ql + qrow * QDIM + (size_t)head * HD + hi * 8;
        #pragma unroll
        for (int db = 0; db < 8; ++db) {
            qfh[db] = *(const s16x8*)(qb + db * 16);
            qfl[db] = *(const s16x8*)(qb2 + db * 16);
        }
    }

    f32x16 acco[4];
    #pragma unroll
    for (int dt = 0; dt < 4; ++dt) acco[dt] = (f32x16)(0.0f);
    float m = -1e30f, l = 0.f;

    const u16* kbase = kh + (size_t)kvh * S_LEN * HD;
    const u16* lbase = kl + (size_t)kvh * S_LEN * HD;
    const u16* vbase = vt + (size_t)kvh * HD * S_LEN;

    auto stage = [&](int kt, int slot) {
        u16* S = SMEM + slot * 12288;
        #pragma unroll
        for (int i = 0; i < 6; ++i) {
            int c = w + 4 * i;
            if (c < 16) {
                int cc = c & 7;
                int u = cc * 64 + lane;
                int krow = u >> 4;
                int kb = (u & 15) ^ (krow & 15);
                size_t g = (size_t)(kt * 32 + krow) * HD + kb * 8;
                if (c < 8) gload16(kbase + g, S + cc * 512);
                else       gload16(lbase + g, S + 4096 + cc * 512);
            } else {
                int cc = c - 16;
                int u = cc * 64 + lane;
                int R = u >> 3, s3 = u & 7;
                int g3 = s3 ^ (R & 7);
                int d = R * 2 + (g3 >> 2);
                int kb = g3 & 3;
                gload16(vbase + (size_t)d * S_LEN + kt * 32 + kb * 8,
                        S + 8192 + cc * 512);
            }
        }
    };

    stage(0, 0);
    if (KT > 1) stage(1, 1);

    for (int kt = 0; kt < KT; ++kt) {
        const int slot = kt % 3;
        __builtin_amdgcn_sched_barrier(0);
        if (kt + 1 < KT) { asm volatile("s_waitcnt vmcnt(6)" ::: "memory"); }
        else             { asm volatile("s_waitcnt vmcnt(0)" ::: "memory"); }
        __builtin_amdgcn_s_barrier();
        __builtin_amdgcn_sched_barrier(0);
        if (kt + 2 < KT) stage(kt + 2, (kt + 2) % 3);

        u16* Khs = SMEM + slot * 12288;
        u16* Kls = Khs + 4096;
        u16* Vts = Khs + 8192;

        f32x16 sfA = (f32x16)(0.0f), sfB = (f32x16)(0.0f);
        __builtin_amdgcn_s_setprio(1);
        #pragma unroll
        for (int d = 0; d < 4; ++d) {
            int u = d * 2 + hi;
            s16x8 a0h = *(const s16x8*)&Khs[lswK(col, u)];
            s16x8 a0l = *(const s16x8*)&Kls[lswK(col, u)];
            sfA = MFMA32(a0h, qfh[d], sfA);
            sfA = MFMA32(a0l, qfh[d], sfA);
            sfA = MFMA32(a0h, qfl[d], sfA);
        }
        #pragma unroll
        for (int d = 4; d < 8; ++d) {
            int u = d * 2 + hi;
            s16x8 a0h = *(const s16x8*)&Khs[lswK(col, u)];
            s16x8 a0l = *(const s16x8*)&Kls[lswK(col, u)];
            sfB = MFMA32(a0h, qfh[d], sfB);
            sfB = MFMA32(a0l, qfh[d], sfB);
            sfB = MFMA32(a0h, qfl[d], sfB);
        }
        __builtin_amdgcn_s_setprio(0);
        f32x16 sf0 = sfA + sfB;

        if (kt == qst) {
            #pragma unroll
            for (int r = 0; r < 16; ++r) {
                int row = (r & 3) + 8 * (r >> 2) + 4 * hi;
                if (row > col) sf0[r] = -1e30f;
            }
        }

        float pm = sf0[0];
        #pragma unroll
        for (int r = 1; r < 16; ++r) pm = fmaxf(pm, sf0[r]);
        pm = fmaxf(pm, __shfl_xor(pm, 32));

        if (!__all(pm - m <= 8.0f)) {
            float mn = fmaxf(m, pm);
            float corr = __expf(m - mn);
            m = mn; l *= corr;
            float cv[16];
            #pragma unroll
            for (int r = 0; r < 16; ++r)
                cv[r] = __shfl(corr, (r & 3) + 8 * (r >> 2) + 4 * hi);
            #pragma unroll
            for (int dt = 0; dt < 4; ++dt)
                #pragma unroll
                for (int r = 0; r < 16; ++r) acco[dt][r] *= cv[r];
        }

        float p0[16], sum = 0.f;
        #pragma unroll
        for (int r = 0; r < 16; ++r) { p0[r] = __expf(sf0[r] - m); sum += p0[r]; }
        sum += __shfl_xor(sum, 32);
        l += sum;

        unsigned w0[8], x0[8];
        #pragma unroll
        for (int i = 0; i < 8; ++i) w0[i] = pk2(p0[2 * i], p0[2 * i + 1]);
        #pragma unroll
        for (int i = 0; i < 8; ++i) x0[i] = __shfl_xor(w0[i], 32);
        union { unsigned u[4]; s16x8 v; } fa;
        s16x8 pa00, pa01;
        fa.u[0] = hi ? x0[2] : w0[0]; fa.u[1] = hi ? x0[3] : w0[1];
        fa.u[2] = hi ? w0[2] : x0[0]; fa.u[3] = hi ? w0[3] : x0[1];
        pa00 = fa.v;
        fa.u[0] = hi ? x0[6] : w0[4]; fa.u[1] = hi ? x0[7] : w0[5];
        fa.u[2] = hi ? w0[6] : x0[4]; fa.u[3] = hi ? w0[7] : x0[5];
        pa01 = fa.v;

        __builtin_amdgcn_s_setprio(1);
        #pragma unroll
        for (int dt = 0; dt < 4; ++dt) {
            int d = dt * 32 + col;
            int R = d >> 1, r7 = R & 7, par = (d & 1) * 4;
            s16x8 vb00 = *(const s16x8*)&Vts[((R << 3) + ((par | hi) ^ r7)) << 3];
            s16x8 vb01 = *(const s16x8*)&Vts[((R << 3) + ((par | (2 + hi)) ^ r7)) << 3];
            acco[dt] = MFMA32(pa00, vb00, acco[dt]);
            acco[dt] = MFMA32(pa01, vb01, acco[dt]);
        }
        __builtin_amdgcn_s_setprio(0);
    }

    __syncthreads();
    float linv = 1.0f / l;
    float lv[16];
    #pragma unroll
    for (int r = 0; r < 16; ++r)
        lv[r] = __shfl(linv, (r & 3) + 8 * (r >> 2) + 4 * hi);

    u16* ob = SMEM;
    #pragma unroll
    for (int dt = 0; dt < 4; ++dt)
        #pragma unroll
        for (int r = 0; r < 16; ++r) {
            int row = (r & 3) + 8 * (r >> 2) + 4 * hi;
            ob[(w * 32 + row) * 128 + dt * 32 + col] = f2bf(acco[dt][r] * lv[r]);
        }
    __syncthreads();
    #pragma unroll
    for (int p = 0; p < 8; ++p) {
        int i = p * 256 + tid;
        int hq = i >> 4, c8 = (i & 15) * 8;
        int hh = hq >> 5, qq = hq & 31;
        size_t grow = (size_t)qst * 32 + qq;
        *(int4*)&aoh[grow * QDIM + (size_t)(kvh * 4 + hh) * HD + c8] =
            *(const int4*)&ob[hq * 128 + c8];
    }
}

// ---------------------------------------------------------------------------
extern "C" void kernel_launch(void* const* d_in, const int* in_sizes, int n_in,
                              void* d_out, int out_size, void* d_ws, size_t ws_size,
                              hipStream_t stream) {
    const float* x   = (const float*)d_in[0];
    const int*   pos = (const int*)d_in[1];
    const float* w_q = (const float*)d_in[2];
    const float* w_k = (const float*)d_in[3];
    const float* w_v = (const float*)d_in[4];
    const float* w_o = (const float*)d_in[5];

    float* out   = (float*)d_out;
    float* out_k = out + (size_t)S_LEN * DMODEL;
    float* out_v = out_k + (size_t)NKV * S_LEN * HD;

    // ---- workspace arena ----
    char* ws = (char*)d_ws;
    size_t off = 0;
    auto alloc = [&](size_t bytes) { char* p = ws + off; off += (bytes + 255) & ~255ull; return p; };
    float* cost = (float*)alloc((size_t)S_LEN * 64 * 4);
    float* sint = (float*)alloc((size_t)S_LEN * 64 * 4);
    float* Q32  = (float*)alloc((size_t)S_LEN * QDIM * 4);       // later: AOH
    u16* XH  = (u16*)alloc((size_t)S_LEN * DMODEL * 2);          // later: KH
    u16* XL  = (u16*)alloc((size_t)S_LEN * DMODEL * 2);          // later: KL
    u16* WBH = (u16*)alloc((size_t)NB * DMODEL * 2);             // later: VT + QL
    u16* WBL = (u16*)alloc((size_t)NB * DMODEL * 2);             // later: QH
    u16* WOH = (u16*)alloc((size_t)DMODEL * QDIM * 2);
    u16* AOH = (u16*)Q32;
    u16* KH  = XH;
    u16* KL  = XL;
    u16* QH  = WBL;
    u16* VT  = WBH;
    u16* QL  = WBH + (size_t)NKV * HD * S_LEN;

    // 1. all input prep (splits + packed WB + rope tables) in one launch
    prep_all<<<PREP_TOTAL / 256, 256, 0, stream>>>(
        x, w_q, w_k, w_v, w_o, pos, XH, XL, WBH, WBL, WOH, cost, sint);

    // 2. fused Q/K/V projections (32x32 MFMA, 2 blocks/CU, 512 blocks)
    gemm_qkv4<<<512, 256, 0, stream>>>(XH, XL, WBH, WBL, Q32, out_k, out_v);

    // 3. V^T + fused rope/scale/split for q and k
    vt_transpose<<<dim3(64, 8), 256, 0, stream>>>(out_v, VT);
    rope_qk_split<<<(S_LEN * (NH + NKV) * 64) / 256, 256, 0, stream>>>(
        Q32, out_k, cost, sint, QH, QL, KH, KL);

    // 4. attention -> bf16 AO (3-slot ring, counted-vmcnt pipeline)
    attn_mfma9<<<512, 256, 0, stream>>>(QH, QL, KH, KL, VT, AOH);

    // 5. O projection (deep-pipelined)
    gemm_o3<<<256, 256, 0, stream>>>(AOH, WOH, out);
}

// Round 13
// 436.192 us; speedup vs baseline: 1.0890x; 1.0890x over previous
//
#include <hip/hip_runtime.h>
#include <math.h>

#define S_LEN 2048
#define DMODEL 2560
#define NH 32
#define NKV 8
#define HD 128
#define QDIM (NH*HD)     // 4096
#define KVDIM (NKV*HD)   // 1024
#define NB (QDIM + 2*KVDIM)   // 6144 packed B rows
#define ROPE_THETA 5000000.0
#define QK_SCALE 0.08838834764831843f

typedef __attribute__((ext_vector_type(8))) short s16x8;
typedef __attribute__((ext_vector_type(4))) float f32x4;
typedef __attribute__((ext_vector_type(16))) float f32x16;
typedef unsigned short u16;

#define MFMA16(a,b,c) __builtin_amdgcn_mfma_f32_16x16x32_bf16((a),(b),(c),0,0,0)
#define MFMA32(a,b,c) __builtin_amdgcn_mfma_f32_32x32x16_bf16((a),(b),(c),0,0,0)

__device__ __forceinline__ u16 f2bf(float x) {
    union { float f; unsigned u; } v; v.f = x;
    unsigned r = v.u + 0x7FFFu + ((v.u >> 16) & 1u);
    return (u16)(r >> 16);
}
__device__ __forceinline__ float bf2f(u16 h) {
    union { unsigned u; float f; } v; v.u = ((unsigned)h) << 16;
    return v.f;
}
__device__ __forceinline__ unsigned pk2(float a, float b) {
    return (unsigned)f2bf(a) | ((unsigned)f2bf(b) << 16);
}

// K arrays: [rows][16 units of 8 bf16], XOR all 4 unit bits.
__device__ __forceinline__ int lswK(int row, int kb) {
    return ((row * 16 + (kb ^ (row & 15))) << 3);
}

// async global->LDS, 16B per lane; LDS dest = wave-uniform base + lane*16.
__device__ __forceinline__ void gload16(const void* g, void* l) {
    __builtin_amdgcn_global_load_lds(
        (const __attribute__((address_space(1))) void*)g,
        (__attribute__((address_space(3))) void*)l, 16, 0, 0);
}

// ---------------------------------------------------------------------------
// prep_all: all input-side elementwise work in ONE launch.
// ---------------------------------------------------------------------------
#define N4_X   (S_LEN*DMODEL/4)
#define N4_WQ  (QDIM*DMODEL/4)
#define N4_WKV (KVDIM*DMODEL/4)
#define N4_WO  (DMODEL*QDIM/4)
#define N_TAB  (S_LEN*64)
#define PREP_TOTAL (N4_X + N4_WQ + N4_WKV + N4_WKV + N4_WO + N_TAB)

__device__ __forceinline__ void split4(const float* in, long i,
                                       u16* hi, u16* lo) {
    float4 v = ((const float4*)in)[i];
    float a[4] = {v.x, v.y, v.z, v.w};
    u16 hh[4], ll[4];
    #pragma unroll
    for (int j = 0; j < 4; ++j) {
        hh[j] = f2bf(a[j]);
        ll[j] = f2bf(a[j] - bf2f(hh[j]));
    }
    ((uint2*)hi)[i] = make_uint2((unsigned)hh[0] | ((unsigned)hh[1] << 16),
                                 (unsigned)hh[2] | ((unsigned)hh[3] << 16));
    ((uint2*)lo)[i] = make_uint2((unsigned)ll[0] | ((unsigned)ll[1] << 16),
                                 (unsigned)ll[2] | ((unsigned)ll[3] << 16));
}
__device__ __forceinline__ void cvt4(const float* in, long i, u16* out) {
    float4 v = ((const float4*)in)[i];
    u16 h0 = f2bf(v.x), h1 = f2bf(v.y), h2 = f2bf(v.z), h3 = f2bf(v.w);
    ((uint2*)out)[i] = make_uint2((unsigned)h0 | ((unsigned)h1 << 16),
                                  (unsigned)h2 | ((unsigned)h3 << 16));
}

__global__ __launch_bounds__(256)
void prep_all(const float* __restrict__ x, const float* __restrict__ w_q,
              const float* __restrict__ w_k, const float* __restrict__ w_v,
              const float* __restrict__ w_o, const int* __restrict__ pos,
              u16* __restrict__ XH, u16* __restrict__ XL,
              u16* __restrict__ WBH, u16* __restrict__ WBL,
              u16* __restrict__ WOH,
              float* __restrict__ cost, float* __restrict__ sint) {
    long i = (long)blockIdx.x * 256 + threadIdx.x;
    if (i < N4_X) { split4(x, i, XH, XL); return; }
    i -= N4_X;
    if (i < N4_WQ) { split4(w_q, i, WBH, WBL); return; }
    i -= N4_WQ;
    if (i < N4_WKV) {
        split4(w_k, i, WBH + (size_t)QDIM * DMODEL, WBL + (size_t)QDIM * DMODEL);
        return;
    }
    i -= N4_WKV;
    if (i < N4_WKV) {
        split4(w_v, i, WBH + (size_t)(QDIM + KVDIM) * DMODEL,
                       WBL + (size_t)(QDIM + KVDIM) * DMODEL);
        return;
    }
    i -= N4_WKV;
    if (i < N4_WO) { cvt4(w_o, i, WOH); return; }
    i -= N4_WO;
    if (i < N_TAB) {
        int s = (int)(i >> 6), j = (int)(i & 63);
        double inv = pow((double)ROPE_THETA, -(double)j / 64.0);
        double ang = (double)pos[s] * inv;
        cost[i] = (float)cos(ang);
        sint[i] = (float)sin(ang);
    }
}

// ---------------------------------------------------------------------------
// merged rope: q (scaled, ws) + k (in-place fp32 cache) -> bf16 hi/lo splits
// ---------------------------------------------------------------------------
__global__ __launch_bounds__(256)
void rope_qk_split(float* __restrict__ q32, float* __restrict__ k,
                   const float* __restrict__ cost, const float* __restrict__ sint,
                   u16* __restrict__ qhh, u16* __restrict__ qll,
                   u16* __restrict__ khh, u16* __restrict__ kll) {
    int idx = blockIdx.x * 256 + threadIdx.x;
    if (idx < S_LEN * NH * 64) {
        int j = idx & 63;
        int h = (idx >> 6) & 31;
        int s = idx >> 11;
        float c = cost[(s << 6) + j], sn = sint[(s << 6) + j];
        size_t base = (size_t)s * QDIM + (size_t)h * HD;
        float x1 = q32[base + j], x2 = q32[base + 64 + j];
        float y1 = (x1 * c - x2 * sn) * QK_SCALE;
        float y2 = (x2 * c + x1 * sn) * QK_SCALE;
        u16 h1 = f2bf(y1), h2 = f2bf(y2);
        qhh[base + j] = h1;      qll[base + j] = f2bf(y1 - bf2f(h1));
        qhh[base + 64 + j] = h2; qll[base + 64 + j] = f2bf(y2 - bf2f(h2));
    } else {
        idx -= S_LEN * NH * 64;
        int j = idx & 63;
        int s = (idx >> 6) & 2047;
        int h = idx >> 17;
        float c = cost[(s << 6) + j], sn = sint[(s << 6) + j];
        size_t base = ((size_t)h * S_LEN + s) * HD;
        float x1 = k[base + j], x2 = k[base + 64 + j];
        float y1 = x1 * c - x2 * sn;
        float y2 = x2 * c + x1 * sn;
        k[base + j] = y1; k[base + 64 + j] = y2;
        u16 h1 = f2bf(y1), h2 = f2bf(y2);
        khh[base + j] = h1;      kll[base + j] = f2bf(y1 - bf2f(h1));
        khh[base + 64 + j] = h2; kll[base + 64 + j] = f2bf(y2 - bf2f(h2));
    }
}

// ---------------------------------------------------------------------------
// V^T builder: v [8][2048][128] fp32 -> vt [8][128][2048] bf16 (coalesced).
// ---------------------------------------------------------------------------
__global__ __launch_bounds__(256)
void vt_transpose(const float* __restrict__ v, u16* __restrict__ vt) {
    __shared__ u16 t[64][80];
    const int kvh = blockIdx.y;
    const int st = blockIdx.x >> 1, dt = blockIdx.x & 1;
    const int tid = threadIdx.x;
    const int r = tid & 15, c4 = (tid >> 4) * 4;
    const float* vb = v + ((size_t)kvh * S_LEN + st * 64) * HD + dt * 64;
    #pragma unroll
    for (int p = 0; p < 4; ++p) {
        int row = p * 16 + r;
        float4 x = *(const float4*)&vb[(size_t)row * HD + c4];
        t[c4 + 0][row] = f2bf(x.x);
        t[c4 + 1][row] = f2bf(x.y);
        t[c4 + 2][row] = f2bf(x.z);
        t[c4 + 3][row] = f2bf(x.w);
    }
    __syncthreads();
    #pragma unroll
    for (int p = 0; p < 2; ++p) {
        int idx = p * 256 + tid;
        int dr = idx >> 3, sc = idx & 7;
        size_t o = ((size_t)kvh * HD + dt * 64 + dr) * S_LEN + st * 64 + sc * 8;
        *(int4*)&vt[o] = *(const int4*)&t[dr][sc * 8];
    }
}

// ---------------------------------------------------------------------------
// gemm_qkv3: deep-pipelined fused QKV projection. Round-11 structure with
// pipeline depth 2 -> 3 (4-slot ring supports lead-3: slot (j+3)&3=(j-1)&3
// whose readers finished before the window-j barrier). Gates count the two
// in-flight stages: vmcnt(8) waves 0-3 (4 loads/stage), vmcnt(6) waves 4-7.
// ---------------------------------------------------------------------------
__global__ __launch_bounds__(512, 2)
void gemm_qkv3(const u16* __restrict__ XH, const u16* __restrict__ XL,
               const u16* __restrict__ WBH, const u16* __restrict__ WBL,
               float* __restrict__ Q32, float* __restrict__ out_k,
               float* __restrict__ out_v) {
    __shared__ u16 SM[57344];        // A: 4 x 8192 u16 | B: 4 x 6144 u16
    const int bid = blockIdx.x;
    const int m0 = (bid & 7) * 256;
    const int n0 = (bid >> 3) * 192;
    const int tid = threadIdx.x, lane = tid & 63, w = tid >> 6;
    const int q4 = lane >> 4, r15 = lane & 15;
    const int wm = (w >> 2) * 128, wn = (w & 3) * 48;

    f32x4 acc[8][3];
    #pragma unroll
    for (int i = 0; i < 8; ++i)
        #pragma unroll
        for (int jj = 0; jj < 3; ++jj) acc[i][jj] = (f32x4)(0.0f);

    auto stageA = [&](int j) {
        const int s = j & 3;
        const int seg = j / 80;
        const int koff = (j - seg * 80) * 32;
        const u16* Ag = (seg == 2) ? XL : XH;
        #pragma unroll
        for (int p = 0; p < 2; ++p) {
            int c = p * 8 + w;
            int u = c * 64 + lane;
            int rl = u >> 3;
            int ulog = (u & 7) ^ (rl & 7);
            int grow = m0 + rl * 2 + (ulog >> 2);
            gload16(Ag + (size_t)grow * DMODEL + koff + (ulog & 3) * 8,
                    &SM[s * 8192 + c * 512]);
        }
    };
    auto stageB = [&](int j) {
        const int s = j & 3;
        const int seg = j / 80;
        const int koff = (j - seg * 80) * 32;
        const u16* Bg = (seg == 1) ? WBL : WBH;
        {
            int u = w * 64 + lane;
            int rl = u >> 3;
            int ulog = (u & 7) ^ (rl & 7);
            int grow = n0 + rl * 2 + (ulog >> 2);
            gload16(Bg + (size_t)grow * DMODEL + koff + (ulog & 3) * 8,
                    &SM[32768 + s * 6144 + w * 512]);
        }
        if (w < 4) {
            int c = 8 + w;
            int u = c * 64 + lane;
            int rl = u >> 3;
            int ulog = (u & 7) ^ (rl & 7);
            int grow = n0 + rl * 2 + (ulog >> 2);
            gload16(Bg + (size_t)grow * DMODEL + koff + (ulog & 3) * 8,
                    &SM[32768 + s * 6144 + c * 512]);
        }
    };

    // prologue: 3 windows in flight
    stageA(0); stageB(0); stageA(1); stageB(1); stageA(2); stageB(2);

    const int NT = 3 * DMODEL / 32;   // 240
    for (int j = 0; j < NT; ++j) {
        const int s = j & 3;
        __builtin_amdgcn_sched_barrier(0);
        if (j + 2 < NT) {
            // outstanding: stages j+1, j+2 (4 or 3 loads each per wave)
            if (w < 4) { asm volatile("s_waitcnt vmcnt(8)" ::: "memory"); }
            else       { asm volatile("s_waitcnt vmcnt(6)" ::: "memory"); }
        } else if (j + 1 < NT) {
            if (w < 4) { asm volatile("s_waitcnt vmcnt(4)" ::: "memory"); }
            else       { asm volatile("s_waitcnt vmcnt(3)" ::: "memory"); }
        } else {
            asm volatile("s_waitcnt vmcnt(0)" ::: "memory");   // tail
        }
        __builtin_amdgcn_s_barrier();
        __builtin_amdgcn_sched_barrier(0);

        if (j + 3 < NT) stageA(j + 3);
        s16x8 bf[3];
        #pragma unroll
        for (int jj = 0; jj < 3; ++jj) {
            int row = wn + jj * 16 + r15;
            int rl = row >> 1, ulog = (row & 1) * 4 + q4;
            bf[jj] = *(const s16x8*)&SM[32768 + s * 6144 + (rl * 8 + (ulog ^ (rl & 7))) * 8];
        }
        s16x8 af[4];
        #pragma unroll
        for (int i = 0; i < 4; ++i) {
            int row = wm + i * 16 + r15;
            int rl = row >> 1, ulog = (row & 1) * 4 + q4;
            af[i] = *(const s16x8*)&SM[s * 8192 + (rl * 8 + (ulog ^ (rl & 7))) * 8];
        }
        __builtin_amdgcn_s_setprio(1);
        #pragma unroll
        for (int i = 0; i < 4; ++i)
            #pragma unroll
            for (int jj = 0; jj < 3; ++jj)
                acc[i][jj] = MFMA16(af[i], bf[jj], acc[i][jj]);
        __builtin_amdgcn_s_setprio(0);

        if (j + 3 < NT) stageB(j + 3);
        s16x8 ag[4];
        #pragma unroll
        for (int i = 0; i < 4; ++i) {
            int row = wm + (i + 4) * 16 + r15;
            int rl = row >> 1, ulog = (row & 1) * 4 + q4;
            ag[i] = *(const s16x8*)&SM[s * 8192 + (rl * 8 + (ulog ^ (rl & 7))) * 8];
        }
        __builtin_amdgcn_s_setprio(1);
        #pragma unroll
        for (int i = 0; i < 4; ++i)
            #pragma unroll
            for (int jj = 0; jj < 3; ++jj)
                acc[i + 4][jj] = MFMA16(ag[i], bf[jj], acc[i + 4][jj]);
        __builtin_amdgcn_s_setprio(0);
    }

    #pragma unroll
    for (int i = 0; i < 8; ++i) {
        #pragma unroll
        for (int jj = 0; jj < 3; ++jj) {
            int col = n0 + wn + jj * 16 + r15;
            #pragma unroll
            for (int r = 0; r < 4; ++r) {
                int row = m0 + wm + i * 16 + q4 * 4 + r;
                float v = acc[i][jj][r];
                if (col < QDIM) {
                    Q32[(size_t)row * QDIM + col] = v;
                } else if (col < QDIM + KVDIM) {
                    int cc = col - QDIM;
                    out_k[((size_t)(cc >> 7) * S_LEN + row) * HD + (cc & 127)] = v;
                } else {
                    int cc = col - QDIM - KVDIM;
                    out_v[((size_t)(cc >> 7) * S_LEN + row) * HD + (cc & 127)] = v;
                }
            }
        }
    }
}

// ---------------------------------------------------------------------------
// gemm_o3: deep-pipelined O projection (round-11, unchanged).
// ---------------------------------------------------------------------------
__global__ __launch_bounds__(256, 2)
void gemm_o3(const u16* __restrict__ AOH, const u16* __restrict__ WOH,
             float* __restrict__ out) {
    __shared__ u16 SM[36864];     // A: 4 x 4096 | B: 4 x 5120 (u16)
    const int bid = blockIdx.x;
    const int m0 = (bid & 15) * 128;
    const int n0 = (bid >> 4) * 160;
    const int tid = threadIdx.x, lane = tid & 63, w = tid >> 6;
    const int q4 = lane >> 4, r15 = lane & 15;
    const int wm = (w >> 1) * 64, wn = (w & 1) * 80;

    f32x4 acc[4][5];
    #pragma unroll
    for (int i = 0; i < 4; ++i)
        #pragma unroll
        for (int jj = 0; jj < 5; ++jj) acc[i][jj] = (f32x4)(0.0f);

    auto stageA = [&](int j) {
        const int s = j & 3;
        const int koff = j * 32;
        #pragma unroll
        for (int p = 0; p < 2; ++p) {
            int c = p * 4 + w;
            int u = c * 64 + lane;
            int rl = u >> 3;
            int ulog = (u & 7) ^ (rl & 7);
            int grow = m0 + rl * 2 + (ulog >> 2);
            gload16(AOH + (size_t)grow * QDIM + koff + (ulog & 3) * 8,
                    &SM[s * 4096 + c * 512]);
        }
    };
    auto stageB = [&](int j) {
        const int s = j & 3;
        const int koff = j * 32;
        #pragma unroll
        for (int p = 0; p < 3; ++p) {
            int c = p * 4 + w;
            if (c < 10) {
                int u = c * 64 + lane;
                int rl = u >> 3;
                int ulog = (u & 7) ^ (rl & 7);
                int grow = n0 + rl * 2 + (ulog >> 2);
                gload16(WOH + (size_t)grow * QDIM + koff + (ulog & 3) * 8,
                        &SM[16384 + s * 5120 + c * 512]);
            }
        }
    };

    stageA(0); stageB(0); stageA(1); stageB(1);

    const int NT = QDIM / 32;     // 128
    for (int j = 0; j < NT; ++j) {
        const int s = j & 3;
        __builtin_amdgcn_sched_barrier(0);
        if (j + 1 < NT) {
            if (w < 2) { asm volatile("s_waitcnt vmcnt(5)" ::: "memory"); }
            else       { asm volatile("s_waitcnt vmcnt(4)" ::: "memory"); }
        } else {
            asm volatile("s_waitcnt vmcnt(0)" ::: "memory");
        }
        __builtin_amdgcn_s_barrier();
        __builtin_amdgcn_sched_barrier(0);

        if (j + 2 < NT) stageA(j + 2);
        s16x8 bf[5];
        #pragma unroll
        for (int jj = 0; jj < 5; ++jj) {
            int row = wn + jj * 16 + r15;
            int rl = row >> 1, ulog = (row & 1) * 4 + q4;
            bf[jj] = *(const s16x8*)&SM[16384 + s * 5120 + (rl * 8 + (ulog ^ (rl & 7))) * 8];
        }
        s16x8 af01[2];
        #pragma unroll
        for (int i = 0; i < 2; ++i) {
            int row = wm + i * 16 + r15;
            int rl = row >> 1, ulog = (row & 1) * 4 + q4;
            af01[i] = *(const s16x8*)&SM[s * 4096 + (rl * 8 + (ulog ^ (rl & 7))) * 8];
        }
        __builtin_amdgcn_s_setprio(1);
        #pragma unroll
        for (int i = 0; i < 2; ++i)
            #pragma unroll
            for (int jj = 0; jj < 5; ++jj)
                acc[i][jj] = MFMA16(af01[i], bf[jj], acc[i][jj]);
        __builtin_amdgcn_s_setprio(0);

        if (j + 2 < NT) stageB(j + 2);
        s16x8 af23[2];
        #pragma unroll
        for (int i = 0; i < 2; ++i) {
            int row = wm + (i + 2) * 16 + r15;
            int rl = row >> 1, ulog = (row & 1) * 4 + q4;
            af23[i] = *(const s16x8*)&SM[s * 4096 + (rl * 8 + (ulog ^ (rl & 7))) * 8];
        }
        __builtin_amdgcn_s_setprio(1);
        #pragma unroll
        for (int i = 0; i < 2; ++i)
            #pragma unroll
            for (int jj = 0; jj < 5; ++jj)
                acc[i + 2][jj] = MFMA16(af23[i], bf[jj], acc[i + 2][jj]);
        __builtin_amdgcn_s_setprio(0);
    }

    #pragma unroll
    for (int i = 0; i < 4; ++i) {
        #pragma unroll
        for (int jj = 0; jj < 5; ++jj) {
            int col = n0 + wn + jj * 16 + r15;
            #pragma unroll
            for (int r = 0; r < 4; ++r) {
                int row = m0 + wm + i * 16 + q4 * 4 + r;
                out[(size_t)row * DMODEL + col] = acc[i][jj][r];
            }
        }
    }
}

// ---------------------------------------------------------------------------
// MFMA flash attention v9 (round-11, unchanged): swapped 32x32 QK^T,
// per-lane softmax, KVBLK=32, 3-slot ring, counted-vmcnt gates.
// ---------------------------------------------------------------------------
__global__ __launch_bounds__(256, 2)
void attn_mfma9(const u16* __restrict__ qh, const u16* __restrict__ ql,
                const u16* __restrict__ kh, const u16* __restrict__ kl,
                const u16* __restrict__ vt, u16* __restrict__ aoh) {
    const int bid = blockIdx.x;
    const int kvh = bid & 7;
    const int s6 = bid >> 3;
    const int qst = (s6 < 32) ? s6 : 95 - s6;
    const int KT = qst + 1;

    const int tid = threadIdx.x, lane = tid & 63, w = tid >> 6;
    const int head = kvh * 4 + w;
    const int col = lane & 31;
    const int hi = lane >> 5;

    __shared__ u16 SMEM[36864];

    s16x8 qfh[8], qfl[8];
    {
        size_t qrow = (size_t)qst * 32 + col;
        const u16* qb  = qh + qrow * QDIM + (size_t)head * HD + hi * 8;
        const u16* qb2 = ql + qrow * QDIM + (size_t)head * HD + hi * 8;
        #pragma unroll
        for (int db = 0; db < 8; ++db) {
            qfh[db] = *(const s16x8*)(qb + db * 16);
            qfl[db] = *(const s16x8*)(qb2 + db * 16);
        }
    }

    f32x16 acco[4];
    #pragma unroll
    for (int dt = 0; dt < 4; ++dt) acco[dt] = (f32x16)(0.0f);
    float m = -1e30f, l = 0.f;

    const u16* kbase = kh + (size_t)kvh * S_LEN * HD;
    const u16* lbase = kl + (size_t)kvh * S_LEN * HD;
    const u16* vbase = vt + (size_t)kvh * HD * S_LEN;

    auto stage = [&](int kt, int slot) {
        u16* S = SMEM + slot * 12288;
        #pragma unroll
        for (int i = 0; i < 6; ++i) {
            int c = w + 4 * i;
            if (c < 16) {
                int cc = c & 7;
                int u = cc * 64 + lane;
                int krow = u >> 4;
                int kb = (u & 15) ^ (krow & 15);
                size_t g = (size_t)(kt * 32 + krow) * HD + kb * 8;
                if (c < 8) gload16(kbase + g, S + cc * 512);
                else       gload16(lbase + g, S + 4096 + cc * 512);
            } else {
                int cc = c - 16;
                int u = cc * 64 + lane;
                int R = u >> 3, s3 = u & 7;
                int g3 = s3 ^ (R & 7);
                int d = R * 2 + (g3 >> 2);
                int kb = g3 & 3;
                gload16(vbase + (size_t)d * S_LEN + kt * 32 + kb * 8,
                        S + 8192 + cc * 512);
            }
        }
    };

    stage(0, 0);
    if (KT > 1) stage(1, 1);

    for (int kt = 0; kt < KT; ++kt) {
        const int slot = kt % 3;
        __builtin_amdgcn_sched_barrier(0);
        if (kt + 1 < KT) { asm volatile("s_waitcnt vmcnt(6)" ::: "memory"); }
        else             { asm volatile("s_waitcnt vmcnt(0)" ::: "memory"); }
        __builtin_amdgcn_s_barrier();
        __builtin_amdgcn_sched_barrier(0);
        if (kt + 2 < KT) stage(kt + 2, (kt + 2) % 3);

        u16* Khs = SMEM + slot * 12288;
        u16* Kls = Khs + 4096;
        u16* Vts = Khs + 8192;

        f32x16 sfA = (f32x16)(0.0f), sfB = (f32x16)(0.0f);
        __builtin_amdgcn_s_setprio(1);
        #pragma unroll
        for (int d = 0; d < 4; ++d) {
            int u = d * 2 + hi;
            s16x8 a0h = *(const s16x8*)&Khs[lswK(col, u)];
            s16x8 a0l = *(const s16x8*)&Kls[lswK(col, u)];
            sfA = MFMA32(a0h, qfh[d], sfA);
            sfA = MFMA32(a0l, qfh[d], sfA);
            sfA = MFMA32(a0h, qfl[d], sfA);
        }
        #pragma unroll
        for (int d = 4; d < 8; ++d) {
            int u = d * 2 + hi;
            s16x8 a0h = *(const s16x8*)&Khs[lswK(col, u)];
            s16x8 a0l = *(const s16x8*)&Kls[lswK(col, u)];
            sfB = MFMA32(a0h, qfh[d], sfB);
            sfB = MFMA32(a0l, qfh[d], sfB);
            sfB = MFMA32(a0h, qfl[d], sfB);
        }
        __builtin_amdgcn_s_setprio(0);
        f32x16 sf0 = sfA + sfB;

        if (kt == qst) {
            #pragma unroll
            for (int r = 0; r < 16; ++r) {
                int row = (r & 3) + 8 * (r >> 2) + 4 * hi;
                if (row > col) sf0[r] = -1e30f;
            }
        }

        float pm = sf0[0];
        #pragma unroll
        for (int r = 1; r < 16; ++r) pm = fmaxf(pm, sf0[r]);
        pm = fmaxf(pm, __shfl_xor(pm, 32));

        if (!__all(pm - m <= 8.0f)) {
            float mn = fmaxf(m, pm);
            float corr = __expf(m - mn);
            m = mn; l *= corr;
            float cv[16];
            #pragma unroll
            for (int r = 0; r < 16; ++r)
                cv[r] = __shfl(corr, (r & 3) + 8 * (r >> 2) + 4 * hi);
            #pragma unroll
            for (int dt = 0; dt < 4; ++dt)
                #pragma unroll
                for (int r = 0; r < 16; ++r) acco[dt][r] *= cv[r];
        }

        float p0[16], sum = 0.f;
        #pragma unroll
        for (int r = 0; r < 16; ++r) { p0[r] = __expf(sf0[r] - m); sum += p0[r]; }
        sum += __shfl_xor(sum, 32);
        l += sum;

        unsigned w0[8], x0[8];
        #pragma unroll
        for (int i = 0; i < 8; ++i) w0[i] = pk2(p0[2 * i], p0[2 * i + 1]);
        #pragma unroll
        for (int i = 0; i < 8; ++i) x0[i] = __shfl_xor(w0[i], 32);
        union { unsigned u[4]; s16x8 v; } fa;
        s16x8 pa00, pa01;
        fa.u[0] = hi ? x0[2] : w0[0]; fa.u[1] = hi ? x0[3] : w0[1];
        fa.u[2] = hi ? w0[2] : x0[0]; fa.u[3] = hi ? w0[3] : x0[1];
        pa00 = fa.v;
        fa.u[0] = hi ? x0[6] : w0[4]; fa.u[1] = hi ? x0[7] : w0[5];
        fa.u[2] = hi ? w0[6] : x0[4]; fa.u[3] = hi ? w0[7] : x0[5];
        pa01 = fa.v;

        __builtin_amdgcn_s_setprio(1);
        #pragma unroll
        for (int dt = 0; dt < 4; ++dt) {
            int d = dt * 32 + col;
            int R = d >> 1, r7 = R & 7, par = (d & 1) * 4;
            s16x8 vb00 = *(const s16x8*)&Vts[((R << 3) + ((par | hi) ^ r7)) << 3];
            s16x8 vb01 = *(const s16x8*)&Vts[((R << 3) + ((par | (2 + hi)) ^ r7)) << 3];
            acco[dt] = MFMA32(pa00, vb00, acco[dt]);
            acco[dt] = MFMA32(pa01, vb01, acco[dt]);
        }
        __builtin_amdgcn_s_setprio(0);
    }

    __syncthreads();
    float linv = 1.0f / l;
    float lv[16];
    #pragma unroll
    for (int r = 0; r < 16; ++r)
        lv[r] = __shfl(linv, (r & 3) + 8 * (r >> 2) + 4 * hi);

    u16* ob = SMEM;
    #pragma unroll
    for (int dt = 0; dt < 4; ++dt)
        #pragma unroll
        for (int r = 0; r < 16; ++r) {
            int row = (r & 3) + 8 * (r >> 2) + 4 * hi;
            ob[(w * 32 + row) * 128 + dt * 32 + col] = f2bf(acco[dt][r] * lv[r]);
        }
    __syncthreads();
    #pragma unroll
    for (int p = 0; p < 8; ++p) {
        int i = p * 256 + tid;
        int hq = i >> 4, c8 = (i & 15) * 8;
        int hh = hq >> 5, qq = hq & 31;
        size_t grow = (size_t)qst * 32 + qq;
        *(int4*)&aoh[grow * QDIM + (size_t)(kvh * 4 + hh) * HD + c8] =
            *(const int4*)&ob[hq * 128 + c8];
    }
}

// ---------------------------------------------------------------------------
extern "C" void kernel_launch(void* const* d_in, const int* in_sizes, int n_in,
                              void* d_out, int out_size, void* d_ws, size_t ws_size,
                              hipStream_t stream) {
    const float* x   = (const float*)d_in[0];
    const int*   pos = (const int*)d_in[1];
    const float* w_q = (const float*)d_in[2];
    const float* w_k = (const float*)d_in[3];
    const float* w_v = (const float*)d_in[4];
    const float* w_o = (const float*)d_in[5];

    float* out   = (float*)d_out;
    float* out_k = out + (size_t)S_LEN * DMODEL;
    float* out_v = out_k + (size_t)NKV * S_LEN * HD;

    // ---- workspace arena ----
    char* ws = (char*)d_ws;
    size_t off = 0;
    auto alloc = [&](size_t bytes) { char* p = ws + off; off += (bytes + 255) & ~255ull; return p; };
    float* cost = (float*)alloc((size_t)S_LEN * 64 * 4);
    float* sint = (float*)alloc((size_t)S_LEN * 64 * 4);
    float* Q32  = (float*)alloc((size_t)S_LEN * QDIM * 4);       // later: AOH
    u16* XH  = (u16*)alloc((size_t)S_LEN * DMODEL * 2);          // later: KH
    u16* XL  = (u16*)alloc((size_t)S_LEN * DMODEL * 2);          // later: KL
    u16* WBH = (u16*)alloc((size_t)NB * DMODEL * 2);             // later: VT + QL
    u16* WBL = (u16*)alloc((size_t)NB * DMODEL * 2);             // later: QH
    u16* WOH = (u16*)alloc((size_t)DMODEL * QDIM * 2);
    u16* AOH = (u16*)Q32;
    u16* KH  = XH;
    u16* KL  = XL;
    u16* QH  = WBL;
    u16* VT  = WBH;
    u16* QL  = WBH + (size_t)NKV * HD * S_LEN;

    // 1. all input prep (splits + packed WB + rope tables) in one launch
    prep_all<<<PREP_TOTAL / 256, 256, 0, stream>>>(
        x, w_q, w_k, w_v, w_o, pos, XH, XL, WBH, WBL, WOH, cost, sint);

    // 2. fused Q/K/V projections (256x192, lead-3 pipelined, 256 blocks)
    gemm_qkv3<<<256, 512, 0, stream>>>(XH, XL, WBH, WBL, Q32, out_k, out_v);

    // 3. V^T + fused rope/scale/split for q and k
    vt_transpose<<<dim3(64, 8), 256, 0, stream>>>(out_v, VT);
    rope_qk_split<<<(S_LEN * (NH + NKV) * 64) / 256, 256, 0, stream>>>(
        Q32, out_k, cost, sint, QH, QL, KH, KL);

    // 4. attention -> bf16 AO (3-slot ring, counted-vmcnt pipeline)
    attn_mfma9<<<512, 256, 0, stream>>>(QH, QL, KH, KL, VT, AOH);

    // 5. O projection (deep-pipelined)
    gemm_o3<<<256, 256, 0, stream>>>(AOH, WOH, out);
}